// Round 6
// baseline (267.703 us; speedup 1.0000x reference)
//
#include <hip/hip_runtime.h>
#include <hip/hip_cooperative_groups.h>

namespace cg = cooperative_groups;

// FP8 e4m3 (IEEE variant, top exponent excluded -> max level 240) fake-quantization:
//   ema = max|x| (whole tensor), s = max(ema/240, 1e-8)
//   xq  = nearest_level(x/s) * s   (ties -> lower-valued level)
//
// Level grid: uniform step 2^(e-3) per binade (clamped to 2^-9 in the subnormal
// region); top binade [128, 240] step 16. All steps are powers of two, so
// nearest-level = ceil(v/step - 0.5) * step with every intermediate exact in f32
// (ties -> lower level = argmin first occurrence). x/s uses IEEE div to bit-match
// the reference's x_scaled.
//
// Single cooperative kernel (R4: two dispatches cost ~10us in bubbles):
//   phase 1: grid-stride absmax -> per-block partial (agent-scope store)
//   grid.sync()
//   phase 2: every block reduces partials (8 KB, L2-hot) -> s, then quantizes
//            with non-temporal stores so the output doesn't evict x from L3.

typedef float f32x4 __attribute__((ext_vector_type(4)));

#define FP8Q_THREADS 256
#define FP8Q_MAXBLOCKS 2048

__device__ __forceinline__ float fp8q_quant1(float x, float s)
{
    float v = x / s;                               // IEEE div: bit-matches reference x/s
    v = fminf(fmaxf(v, -240.0f), 240.0f);          // saturate at max level (E=1..14 only)
    float m = fabsf(v);
    int e  = (int)(__float_as_uint(m) >> 23) - 127; // unbiased exponent (m=0 -> -127)
    int se = e - 3;                                 // step = 2^(e-3) within binade
    if (se < -9) se = -9;                           // subnormal region: uniform step 2^-9
    float step     = __uint_as_float((unsigned int)(se + 127) << 23);
    float inv_step = __uint_as_float((unsigned int)(127 - se) << 23);
    float k = v * inv_step;                         // exact (pow2 scale), |k| <= 16
    float n = ceilf(k - 0.5f);                      // round-half-to-lower-value (ref tie rule)
    return (n * step) * s;                          // n*step is exactly the level
}

__global__ __launch_bounds__(FP8Q_THREADS) void fp8q_fused_kernel(
    const f32x4* __restrict__ x4, f32x4* __restrict__ o4,
    const float* __restrict__ x_tail, float* __restrict__ o_tail,
    float* __restrict__ partials, int n4, int ntail)
{
    __shared__ float smem[FP8Q_THREADS / 64];
    int tid = blockIdx.x * blockDim.x + threadIdx.x;
    int stride = gridDim.x * blockDim.x;

    // ---- phase 1: absmax ----
    float m = 0.0f;
    for (int i = tid; i < n4; i += stride) {
        f32x4 v = x4[i];
        m = fmaxf(m, fmaxf(fmaxf(fabsf(v.x), fabsf(v.y)),
                           fmaxf(fabsf(v.z), fabsf(v.w))));
    }
    if (tid < ntail) m = fmaxf(m, fabsf(x_tail[tid]));  // leftover (<4) elements
    #pragma unroll
    for (int off = 32; off > 0; off >>= 1)
        m = fmaxf(m, __shfl_xor(m, off));
    if ((threadIdx.x & 63) == 0) smem[threadIdx.x >> 6] = m;
    __syncthreads();
    if (threadIdx.x == 0) {
        float mm = smem[0];
        #pragma unroll
        for (int w = 1; w < FP8Q_THREADS / 64; ++w) mm = fmaxf(mm, smem[w]);
        // agent-scope store: visible across XCDs at the coherence point
        __hip_atomic_store(&partials[blockIdx.x], mm, __ATOMIC_RELAXED,
                           __HIP_MEMORY_SCOPE_AGENT);
    }

    cg::this_grid().sync();

    // ---- all blocks: reduce partials -> s (redundant, L2-hot, ~1us) ----
    float mp = 0.0f;
    for (int i = threadIdx.x; i < (int)gridDim.x; i += blockDim.x)
        mp = fmaxf(mp, __hip_atomic_load(&partials[i], __ATOMIC_RELAXED,
                                         __HIP_MEMORY_SCOPE_AGENT));
    #pragma unroll
    for (int off = 32; off > 0; off >>= 1)
        mp = fmaxf(mp, __shfl_xor(mp, off));
    if ((threadIdx.x & 63) == 0) smem[threadIdx.x >> 6] = mp;  // block synced by grid.sync
    __syncthreads();
    float mm = smem[0];
    #pragma unroll
    for (int w = 1; w < FP8Q_THREADS / 64; ++w) mm = fmaxf(mm, smem[w]);
    float s = fmaxf(mm / 240.0f, 1e-8f);            // 240 + 1e-12 == 240.0f in f32

    // ---- phase 2: quantize ----
    for (int i = tid; i < n4; i += stride) {
        f32x4 v = x4[i];
        f32x4 r;
        r.x = fp8q_quant1(v.x, s);
        r.y = fp8q_quant1(v.y, s);
        r.z = fp8q_quant1(v.z, s);
        r.w = fp8q_quant1(v.w, s);
        __builtin_nontemporal_store(r, &o4[i]);     // don't evict x from L3
    }
    if (tid < ntail) o_tail[tid] = fp8q_quant1(x_tail[tid], s);
}

extern "C" void kernel_launch(void* const* d_in, const int* in_sizes, int n_in,
                              void* d_out, int out_size, void* d_ws, size_t ws_size,
                              hipStream_t stream)
{
    const float* x = (const float*)d_in[0];
    float* out = (float*)d_out;
    int n = in_sizes[0];
    int n4 = n >> 2;
    int ntail = n & 3;
    const float* x_tail = x + (size_t)n4 * 4;
    float* o_tail = out + (size_t)n4 * 4;
    float* partials = (float*)d_ws;   // one float per block

    // cooperative grid: cap at co-resident capacity (occupancy query, capture-safe)
    int dev = 0;
    (void)hipGetDevice(&dev);
    int num_cu = 256;
    (void)hipDeviceGetAttribute(&num_cu, hipDeviceAttributeMultiprocessorCount, dev);
    int max_per_cu = 4;
    (void)hipOccupancyMaxActiveBlocksPerMultiprocessor(&max_per_cu, fp8q_fused_kernel,
                                                       FP8Q_THREADS, 0);
    if (max_per_cu < 1) max_per_cu = 1;

    int blocks = (n4 + FP8Q_THREADS - 1) / FP8Q_THREADS;
    if (blocks > FP8Q_MAXBLOCKS) blocks = FP8Q_MAXBLOCKS;
    if (blocks > max_per_cu * num_cu) blocks = max_per_cu * num_cu;
    if (blocks < 1) blocks = 1;

    const f32x4* x4 = (const f32x4*)x;
    f32x4* o4 = (f32x4*)out;
    void* args[] = { (void*)&x4, (void*)&o4, (void*)&x_tail, (void*)&o_tail,
                     (void*)&partials, (void*)&n4, (void*)&ntail };
    (void)hipLaunchCooperativeKernel((void*)fp8q_fused_kernel, dim3(blocks),
                                     dim3(FP8Q_THREADS), args, 0, stream);
}

// Round 7
// 68.393 us; speedup vs baseline: 3.9142x; 3.9142x over previous
//
#include <hip/hip_runtime.h>

// FP8 e4m3 (IEEE variant, top exponent excluded -> max level 240) fake-quantization:
//   ema = max|x| (whole tensor), s = max(ema/240, 1e-8)
//   xq  = nearest_level(x/s) * s   (ties -> lower-valued level)
//
// Level grid: uniform step 2^(e-3) per binade (clamped to 2^-9 in the subnormal
// region); top binade [128, 240] step 16. All steps are powers of two, so
// nearest-level = ceil(v/step - 0.5) * step with every intermediate exact in f32
// (ties -> lower level = argmin first occurrence). x/s uses IEEE div to bit-match
// the reference's x_scaled.
//
// Structure (2 plain kernels — R6 showed cooperative grid.sync costs 3.3x per-byte):
//   A: per-block absmax -> partials[block] (plain stores, no atomics: R2 showed
//      single-address atomics serialize at ~15ns each).
//   B: every block redundantly reduces the 2048 partials (8 KB, L3-hot, ~2us
//      overlapped) -> s, then quantizes with NON-TEMPORAL stores so the 134 MB
//      output doesn't evict x from the 256 MB L3 before pass-2 re-reads it.

typedef float f32x4 __attribute__((ext_vector_type(4)));

#define FP8Q_THREADS 256
#define FP8Q_MAXBLOCKS 2048

__global__ __launch_bounds__(FP8Q_THREADS) void fp8q_absmax_kernel(
    const f32x4* __restrict__ x4, float* __restrict__ partials,
    const float* __restrict__ x_tail, int n4, int ntail)
{
    __shared__ float smem[FP8Q_THREADS / 64];
    int tid = blockIdx.x * blockDim.x + threadIdx.x;
    int stride = gridDim.x * blockDim.x;

    // 2-way unrolled grid-stride: two independent 16B loads in flight per iter
    float ma = 0.0f, mb = 0.0f;
    int i = tid;
    for (; i + stride < n4; i += 2 * stride) {
        f32x4 a = x4[i];
        f32x4 b = x4[i + stride];
        ma = fmaxf(ma, fmaxf(fmaxf(fabsf(a.x), fabsf(a.y)),
                             fmaxf(fabsf(a.z), fabsf(a.w))));
        mb = fmaxf(mb, fmaxf(fmaxf(fabsf(b.x), fabsf(b.y)),
                             fmaxf(fabsf(b.z), fabsf(b.w))));
    }
    if (i < n4) {
        f32x4 a = x4[i];
        ma = fmaxf(ma, fmaxf(fmaxf(fabsf(a.x), fabsf(a.y)),
                             fmaxf(fabsf(a.z), fabsf(a.w))));
    }
    float m = fmaxf(ma, mb);
    if (tid < ntail) m = fmaxf(m, fabsf(x_tail[tid]));  // leftover (<4) elements

    #pragma unroll
    for (int off = 32; off > 0; off >>= 1)
        m = fmaxf(m, __shfl_xor(m, off));
    if ((threadIdx.x & 63) == 0) smem[threadIdx.x >> 6] = m;
    __syncthreads();
    if (threadIdx.x == 0) {
        float mm = smem[0];
        #pragma unroll
        for (int w = 1; w < FP8Q_THREADS / 64; ++w) mm = fmaxf(mm, smem[w]);
        partials[blockIdx.x] = mm;   // one plain store per block
    }
}

__device__ __forceinline__ float fp8q_quant1(float x, float s)
{
    float v = x / s;                               // IEEE div: bit-matches reference x/s
    v = fminf(fmaxf(v, -240.0f), 240.0f);          // saturate at max level (E=1..14 only)
    float m = fabsf(v);
    int e  = (int)(__float_as_uint(m) >> 23) - 127; // unbiased exponent (m=0 -> -127)
    int se = e - 3;                                 // step = 2^(e-3) within binade
    if (se < -9) se = -9;                           // subnormal region: uniform step 2^-9
    float step     = __uint_as_float((unsigned int)(se + 127) << 23);
    float inv_step = __uint_as_float((unsigned int)(127 - se) << 23);
    float k = v * inv_step;                         // exact (pow2 scale), |k| <= 16
    float n = ceilf(k - 0.5f);                      // round-half-to-lower-value (ref tie rule)
    return (n * step) * s;                          // n*step is exactly the level
}

__global__ __launch_bounds__(FP8Q_THREADS) void fp8q_quant_kernel(
    const f32x4* __restrict__ x4, f32x4* __restrict__ o4,
    const float* __restrict__ x_tail, float* __restrict__ o_tail,
    const f32x4* __restrict__ partials4, int np4, int n4, int ntail)
{
    __shared__ float smem[FP8Q_THREADS / 64];
    __shared__ float s_shared;
    // redundant per-block reduce of block partials (vectorized; L3-hot)
    float m = 0.0f;
    for (int i = threadIdx.x; i < np4; i += FP8Q_THREADS) {
        f32x4 p = partials4[i];
        m = fmaxf(m, fmaxf(fmaxf(p.x, p.y), fmaxf(p.z, p.w)));
    }
    #pragma unroll
    for (int off = 32; off > 0; off >>= 1)
        m = fmaxf(m, __shfl_xor(m, off));
    if ((threadIdx.x & 63) == 0) smem[threadIdx.x >> 6] = m;
    __syncthreads();
    if (threadIdx.x == 0) {
        float mm = smem[0];
        #pragma unroll
        for (int w = 1; w < FP8Q_THREADS / 64; ++w) mm = fmaxf(mm, smem[w]);
        s_shared = fmaxf(mm / 240.0f, 1e-8f);      // 240 + 1e-12 == 240.0f in f32
    }
    __syncthreads();
    float s = s_shared;

    int tid = blockIdx.x * blockDim.x + threadIdx.x;
    int stride = gridDim.x * blockDim.x;
    for (int i = tid; i < n4; i += stride) {
        f32x4 v = x4[i];
        f32x4 r;
        r.x = fp8q_quant1(v.x, s);
        r.y = fp8q_quant1(v.y, s);
        r.z = fp8q_quant1(v.z, s);
        r.w = fp8q_quant1(v.w, s);
        __builtin_nontemporal_store(r, &o4[i]);    // don't evict x from L3
    }
    if (tid < ntail) o_tail[tid] = fp8q_quant1(x_tail[tid], s);
}

extern "C" void kernel_launch(void* const* d_in, const int* in_sizes, int n_in,
                              void* d_out, int out_size, void* d_ws, size_t ws_size,
                              hipStream_t stream)
{
    const float* x = (const float*)d_in[0];
    float* out = (float*)d_out;
    int n = in_sizes[0];
    int n4 = n >> 2;
    int ntail = n & 3;
    const float* x_tail = x + (size_t)n4 * 4;
    float* o_tail = out + (size_t)n4 * 4;

    float* partials = (float*)d_ws;   // one float per block, padded to x4 multiple

    int blocks = (n4 + FP8Q_THREADS - 1) / FP8Q_THREADS;
    if (blocks > FP8Q_MAXBLOCKS) blocks = FP8Q_MAXBLOCKS;
    if (blocks < 1) blocks = 1;

    // pad partials to a multiple of 4 with zeros so quant can read f32x4
    int npad = (blocks + 3) & ~3;
    hipMemsetAsync(partials + blocks, 0, (size_t)(npad - blocks) * sizeof(float), stream);

    fp8q_absmax_kernel<<<blocks, FP8Q_THREADS, 0, stream>>>(
        (const f32x4*)x, partials, x_tail, n4, ntail);
    fp8q_quant_kernel<<<blocks, FP8Q_THREADS, 0, stream>>>(
        (const f32x4*)x, (f32x4*)out, x_tail, o_tail,
        (const f32x4*)partials, npad >> 2, n4, ntail);
}